// Round 11
// baseline (242.351 us; speedup 1.0000x reference)
//
#include <hip/hip_runtime.h>

// Problem constants: B=8, C=4, H=W=512, K_ITERS=10, ALPHA=2
#define Wd   512
#define W4   128               // float4 granules per row (fp32 path)
#define W8   64                // half8 granules per row (fp16 path)
#define HWp  262144            // elements per (b,c) plane
#define NTOT 8388608           // B*C*H*W

#define NB   16                // blocks per plane (persistent path)
#define OWN  32                // owned rows per block
#define GST  10                // ghost rows per side (one per pass)
#define MAXR 52                // OWN + 2*GST

#define F_INF __int_as_float(0x7F800000)

typedef _Float16 half8 __attribute__((ext_vector_type(8)));
typedef _Float16 half4v __attribute__((ext_vector_type(4)));

// red[] layout (960 floats, ALL zero-init; per-iteration slots):
//   cmn[k][plane] = red[k*32 + plane]        unsigned ~bits(min)
//   mx [k][plane] = red[320 + k*32 + plane]  float bits, signed atomicMax
//   sm [k][plane] = red[640 + k*32 + plane]  float atomicAdd
// pcnt: 9*32 per-(pass,plane) arrival counters, padded to 64B stride
// done: 1 counter (final arrival)

// ---------------------------------------------------------------- helpers

__device__ __forceinline__ float4 bound4(const float* __restrict__ pred,
                                         const int* __restrict__ target,
                                         int plane, int v)
{
    const int b = plane >> 2, c = plane & 3;
    float4 p = ((const float4*)(pred + (size_t)plane * HWp))[v];
    int4   t = ((const int4*)(target + (size_t)b * HWp))[v];
    float dx = p.x - (t.x == c ? 1.0f : 0.0f);
    float dy = p.y - (t.y == c ? 1.0f : 0.0f);
    float dz = p.z - (t.z == c ? 1.0f : 0.0f);
    float dw = p.w - (t.w == c ? 1.0f : 0.0f);
    return make_float4(dx*dx, dy*dy, dz*dz, dw*dw);
}

__device__ __forceinline__ float bound1(const float* __restrict__ pred,
                                        const int* __restrict__ target,
                                        int plane, int i)
{
    const int b = plane >> 2, c = plane & 3;
    float p = pred[(size_t)plane * HWp + i];
    int   t = target[(size_t)b * HWp + i];
    float d = p - (t == c ? 1.0f : 0.0f);
    return d * d;
}

template <int NW>
__device__ __forceinline__ void block_reduce_commit(float lmin, float lmax,
                                                    float lsum,
                                                    float* __restrict__ red,
                                                    int k, int plane)
{
    for (int off = 32; off > 0; off >>= 1) {
        lmin = fminf(lmin, __shfl_down(lmin, off));
        lmax = fmaxf(lmax, __shfl_down(lmax, off));
        lsum += __shfl_down(lsum, off);
    }
    __shared__ float smin[NW], smax[NW], ssum[NW];
    const int wave = threadIdx.x >> 6;
    if ((threadIdx.x & 63) == 0) { smin[wave] = lmin; smax[wave] = lmax; ssum[wave] = lsum; }
    __syncthreads();
    if (threadIdx.x == 0) {
        float bmin = smin[0], bmax = smax[0], bsum = ssum[0];
        #pragma unroll
        for (int i = 1; i < NW; i++) {
            bmin = fminf(bmin, smin[i]);
            bmax = fmaxf(bmax, smax[i]);
            bsum += ssum[i];
        }
        atomicMax((unsigned*)&red[k * 32 + plane], ~__float_as_uint(bmin));
        atomicMax((int*)&red[320 + k * 32 + plane], __float_as_int(bmax));
        atomicAdd(&red[640 + k * 32 + plane], bsum);
    }
}

// ======================= persistent LDS-resident path =======================
// 512 blocks (16 per plane) x 512 threads, cooperative launch (residency
// guarantee only -- NO grid.sync). Each block stages its 52-row fp16 region
// (32 owned + 10 ghost/side) in LDS once, then runs all 10 stencil passes
// in-LDS on a shrinking trapezoid (ghost recompute = no bulk halo exchange).
// Only 3 scalars/plane/pass cross blocks, via device atomics + a 16-block
// per-plane spin barrier. LDS state is immune to the fences' cache
// invalidations (the R2 grid.sync pathology). Global traffic: inputs once.
__global__ __launch_bounds__(512) void hausdorff_persist(
    const float* __restrict__ pred, const int* __restrict__ target,
    float* __restrict__ out, float* __restrict__ red,
    unsigned* __restrict__ pcnt, unsigned* __restrict__ done)
{
    const int bid   = blockIdx.x;
    const int plane = bid >> 4;            // 0..31
    const int binp  = bid & 15;            // 0..15
    const int A     = binp * OWN;          // owned rows [A, A+32)
    const int rl    = (A - GST < 0) ? 0 : A - GST;
    const int rh    = (A + OWN + GST > Wd) ? Wd : A + OWN + GST;

    const int tid  = threadIdx.x;
    const int lane = tid & 63;             // col8 (half8 column)
    const int w    = tid >> 6;             // wave 0..7

    __shared__ _Float16 tile[MAXR][Wd];    // 53 KB region
    __shared__ _Float16 spare[Wd];         // old copy of group-boundary row
    __shared__ float bc0, bc1;             // (s,o) broadcast

    const int   b  = plane >> 2, c = plane & 3;
    const float* pp = pred   + (size_t)plane * HWp;
    const int*   tp = target + (size_t)b * HWp;

    // ---- init: bound = (pred-onehot)^2 -> fp16 LDS (read inputs ONCE) ----
    for (int r = rl + w; r < rh; r += 8) {
        const int base = r * Wd + lane * 8;
        float4 p0 = *(const float4*)(pp + base);
        float4 p1 = *(const float4*)(pp + base + 4);
        int4   t0 = *(const int4*)(tp + base);
        int4   t1 = *(const int4*)(tp + base + 4);
        half8 hv;
        float d;
        d = p0.x - (t0.x == c ? 1.0f : 0.0f); hv[0] = (_Float16)(d * d);
        d = p0.y - (t0.y == c ? 1.0f : 0.0f); hv[1] = (_Float16)(d * d);
        d = p0.z - (t0.z == c ? 1.0f : 0.0f); hv[2] = (_Float16)(d * d);
        d = p0.w - (t0.w == c ? 1.0f : 0.0f); hv[3] = (_Float16)(d * d);
        d = p1.x - (t1.x == c ? 1.0f : 0.0f); hv[4] = (_Float16)(d * d);
        d = p1.y - (t1.y == c ? 1.0f : 0.0f); hv[5] = (_Float16)(d * d);
        d = p1.z - (t1.z == c ? 1.0f : 0.0f); hv[6] = (_Float16)(d * d);
        d = p1.w - (t1.w == c ? 1.0f : 0.0f); hv[7] = (_Float16)(d * d);
        ((half8*)&tile[r - rl][0])[lane] = hv;
    }
    __syncthreads();

    const bool hasL = (lane > 0);
    const bool hasR = (lane < W8 - 1);

    float s = 1.0f, o = 0.0f;
    for (int k = 0; k < 10; k++) {
        const int g  = 9 - k;              // remaining ghost margin
        int lo = A - g;        if (lo < 0)  lo = 0;
        int hi = A + OWN + g;  if (hi > Wd) hi = Wd;

        float lmin = F_INF, lmax = 0.0f, lsum = 0.0f;

        // 8-row groups: read-all -> sync -> write-all (in-place safe; the
        // group's top neighbor row, overwritten last group, comes from spare)
        const int ng = (hi - lo + 7) >> 3;
        for (int gg = 0; gg < ng; gg++) {
            const int  r      = lo + gg * 8 + w;
            const bool active = (r < hi);                  // wave-uniform
            half8 u8 = (half8)(_Float16)0, c8 = u8, d8 = u8;
            bool stash = false;
            int  li = 0;
            if (active) {
                li = r - rl;
                c8 = ((const half8*)&tile[li][0])[lane];
                if (r > 0) {
                    if (w == 0 && gg > 0) u8 = ((const half8*)&spare[0])[lane];
                    else                  u8 = ((const half8*)&tile[li - 1][0])[lane];
                }
                if (r < Wd - 1) d8 = ((const half8*)&tile[li + 1][0])[lane];
                stash = (w == 7) && (lo + (gg + 1) * 8 < hi);
            }
            __syncthreads();
            if (active) {
                float uf[8], cf[8], df[8];
                #pragma unroll
                for (int j = 0; j < 8; j++) {
                    uf[j] = (float)u8[j]; cf[j] = (float)c8[j]; df[j] = (float)d8[j];
                }
                float lft = __shfl_up(cf[7], 1);
                float rgt = __shfl_down(cf[0], 1);
                if (!hasL) lft = 0.0f;
                if (!hasR) rgt = 0.0f;

                const bool hasU = (r > 0), hasD = (r < Wd - 1);
                const float vc = (hasU ? 1.0f : 0.0f) + (hasD ? 1.0f : 0.0f);
                const bool owned = (r >= A) && (r < A + OWN);  // wave-uniform
                half8 eh;
                #pragma unroll
                for (int j = 0; j < 8; j++) {
                    const float lnb = (j == 0) ? lft : cf[j - 1];
                    const float rnb = (j == 7) ? rgt : cf[j + 1];
                    const bool  hl  = (j > 0) || hasL;
                    const bool  hr  = (j < 7) || hasR;
                    float sum = cf[j] + lnb + rnb + uf[j] + df[j];
                    float cnt = 1.0f + (hl ? 1.0f : 0.0f) + (hr ? 1.0f : 0.0f) + vc;
                    float e = fmaxf(0.2f * (s * sum + o * cnt) - 0.5f, 0.0f);
                    _Float16 h = (_Float16)e;
                    eh[j] = h;
                    if (owned) {
                        float er = (float)h;
                        lmin = fminf(lmin, er);
                        lmax = fmaxf(lmax, er);
                        lsum += er;
                    }
                }
                ((half8*)&tile[li][0])[lane] = eh;
                if (stash) ((half8*)&spare[0])[lane] = c8;  // old row for next group
            }
            __syncthreads();
        }

        block_reduce_commit<8>(lmin, lmax, lsum, red, k, plane);

        if (tid == 0) {
            __threadfence();               // commits visible before arrival
            if (k < 9) {
                unsigned* ctr = &pcnt[(k * 32 + plane) * 16];
                atomicAdd(ctr, 1u);
                unsigned iters = 0;
                while (__hip_atomic_load(ctr, __ATOMIC_RELAXED,
                                         __HIP_MEMORY_SCOPE_AGENT) < (unsigned)NB) {
                    __builtin_amdgcn_s_sleep(2);
                    if (++iters > (1u << 24)) break;   // hang guard
                }
                __threadfence();           // acquire: refetch coherently
                float mn = __uint_as_float(~((volatile unsigned*)red)[k * 32 + plane]);
                float mx = ((volatile float*)red)[320 + k * 32 + plane];
                float denom = mx - mn;
                float ss = 1.0f, oo = 0.0f;
                if (denom != 0.0f) { ss = 1.0f / denom; oo = -mn / denom; }
                bc0 = ss; bc1 = oo;
            } else {
                atomicAdd(done, 1u);
            }
        }
        __syncthreads();
        if (k < 9) { s = bc0; o = bc1; }
    }

    // ---- epilogue: the designated block folds red[] into the loss ----
    if (bid != 0) return;
    if (tid == 0) {
        unsigned iters = 0;
        while (__hip_atomic_load(done, __ATOMIC_RELAXED,
                                 __HIP_MEMORY_SCOPE_AGENT) < 512u) {
            __builtin_amdgcn_s_sleep(2);
            if (++iters > (1u << 24)) break;
        }
        __threadfence();
    }
    __syncthreads();
    if (tid < 64) {
        float contrib = 0.0f;
        if (tid < 32) {
            #pragma unroll
            for (int kk = 0; kk < 10; kk++) {
                float mn = __uint_as_float(~((volatile unsigned*)red)[kk * 32 + tid]);
                float mx = ((volatile float*)red)[320 + kk * 32 + tid];
                float sm = ((volatile float*)red)[640 + kk * 32 + tid];
                float denom = mx - mn;
                float ss = 1.0f, oo = 0.0f;
                if (denom != 0.0f) { ss = 1.0f / denom; oo = -mn / denom; }
                float wgt = (float)((kk + 1) * (kk + 1));
                contrib += (ss * sm + oo * 262144.0f) * wgt;
            }
        }
        for (int off = 16; off > 0; off >>= 1)
            contrib += __shfl_down(contrib, off);
        if (tid == 0) out[0] = contrib / 8388608.0f;
    }
}

// ======================= fallback: R10 multi-launch path =======================

__global__ __launch_bounds__(256) void stencil_first(const float* __restrict__ pred,
                                                     const int* __restrict__ target,
                                                     _Float16* __restrict__ out,
                                                     float* __restrict__ red)
{
    const int plane = blockIdx.y;
    const int chunk = blockIdx.x;              // 16 rows per chunk

    _Float16* op = out + (size_t)plane * HWp;

    const int col4 = threadIdx.x & 127;
    const int rsub = threadIdx.x >> 7;

    float lmin = F_INF, lmax = 0.0f, lsum = 0.0f;
    const bool hasL = (col4 > 0);
    const bool hasR = (col4 < W4 - 1);

    #pragma unroll
    for (int p = 0; p < 8; p++) {
        const int row = chunk * 16 + p * 2 + rsub;
        const int v   = row * W4 + col4;
        const bool hasU = (row > 0);
        const bool hasD = (row < Wd - 1);

        float4 c4 = bound4(pred, target, plane, v);
        float4 u4 = hasU ? bound4(pred, target, plane, v - W4) : make_float4(0,0,0,0);
        float4 d4 = hasD ? bound4(pred, target, plane, v + W4) : make_float4(0,0,0,0);
        float lft = hasL ? bound1(pred, target, plane, 4*v - 1) : 0.0f;
        float rgt = hasR ? bound1(pred, target, plane, 4*v + 4) : 0.0f;

        float4 sum;
        sum.x = c4.x + c4.y + u4.x + d4.x + lft;
        sum.y = c4.x + c4.y + c4.z + u4.y + d4.y;
        sum.z = c4.y + c4.z + c4.w + u4.z + d4.z;
        sum.w = c4.z + c4.w + rgt + u4.w + d4.w;

        float4 e;
        e.x = fmaxf(0.2f * sum.x - 0.5f, 0.0f);   // k=0: s=1, o=0
        e.y = fmaxf(0.2f * sum.y - 0.5f, 0.0f);
        e.z = fmaxf(0.2f * sum.z - 0.5f, 0.0f);
        e.w = fmaxf(0.2f * sum.w - 0.5f, 0.0f);

        half4v h;
        h[0] = (_Float16)e.x; h[1] = (_Float16)e.y;
        h[2] = (_Float16)e.z; h[3] = (_Float16)e.w;
        ((half4v*)op)[v] = h;

        float r0 = (float)h[0], r1 = (float)h[1], r2 = (float)h[2], r3 = (float)h[3];
        lmin = fminf(lmin, fminf(fminf(r0, r1), fminf(r2, r3)));
        lmax = fmaxf(lmax, fmaxf(fmaxf(r0, r1), fmaxf(r2, r3)));
        lsum += (r0 + r1) + (r2 + r3);
    }

    block_reduce_commit<4>(lmin, lmax, lsum, red, 0, plane);
}

__global__ __launch_bounds__(512) void stencil_h(const _Float16* __restrict__ in,
                                                 _Float16* __restrict__ out,
                                                 float* __restrict__ red,
                                                 int k, int store)
{
    const int plane = blockIdx.y;
    const int chunk = blockIdx.x;              // 16 rows per chunk

    float mn = __uint_as_float(~((const unsigned*)red)[(k - 1) * 32 + plane]);
    float mx = red[320 + (k - 1) * 32 + plane];
    float denom = mx - mn;
    float s = 1.0f, o = 0.0f;
    if (denom != 0.0f) { s = 1.0f / denom; o = -mn / denom; }

    const _Float16* ip = in  + (size_t)plane * HWp;
    _Float16*       op = out + (size_t)plane * HWp;

    const int col8 = threadIdx.x & 63;
    const int wv   = threadIdx.x >> 6;
    const int r0   = chunk * 16 + wv * 2;
    const int v0   = r0 * W8 + col8;

    const bool hasL  = (col8 > 0);
    const bool hasR  = (col8 < W8 - 1);
    const bool hasU0 = (r0 > 0);
    const bool hasD1 = (r0 + 2 < Wd);

    half8 u8 = hasU0 ? ((const half8*)ip)[v0 - W8]     : (half8)(_Float16)0;
    half8 c0 = ((const half8*)ip)[v0];
    half8 c1 = ((const half8*)ip)[v0 + W8];
    half8 d8 = hasD1 ? ((const half8*)ip)[v0 + 2 * W8] : (half8)(_Float16)0;

    float uf[8], f0[8], f1[8], df[8];
    #pragma unroll
    for (int j = 0; j < 8; j++) {
        uf[j] = (float)u8[j];
        f0[j] = (float)c0[j]; f1[j] = (float)c1[j];
        df[j] = (float)d8[j];
    }

    float lmin = F_INF, lmax = 0.0f, lsum = 0.0f;

    auto PROC = [&](const float* up, const float* cen, const float* dn, int row) {
        const bool hasU = (row > 0);
        const bool hasD = (row < Wd - 1);
        float lft = __shfl_up(cen[7], 1);
        float rgt = __shfl_down(cen[0], 1);
        if (!hasL) lft = 0.0f;
        if (!hasR) rgt = 0.0f;

        const float vc = (hasU ? 1.0f : 0.0f) + (hasD ? 1.0f : 0.0f);
        half8 eh;
        #pragma unroll
        for (int j = 0; j < 8; j++) {
            const float lnb = (j == 0) ? lft : cen[j - 1];
            const float rnb = (j == 7) ? rgt : cen[j + 1];
            const bool  hl  = (j > 0) || hasL;
            const bool  hr  = (j < 7) || hasR;
            float sum = cen[j] + lnb + rnb + up[j] + dn[j];
            float cnt = 1.0f + (hl ? 1.0f : 0.0f) + (hr ? 1.0f : 0.0f) + vc;
            float e = fmaxf(0.2f * (s * sum + o * cnt) - 0.5f, 0.0f);
            _Float16 h = (_Float16)e;
            eh[j] = h;
            float er = (float)h;
            lmin = fminf(lmin, er);
            lmax = fmaxf(lmax, er);
            lsum += er;
        }
        if (store) ((half8*)op)[row * W8 + col8] = eh;
    };

    PROC(uf, f0, f1, r0);
    PROC(f0, f1, df, r0 + 1);

    block_reduce_commit<8>(lmin, lmax, lsum, red, k, plane);
}

__global__ void final_out(const float* __restrict__ red, float* __restrict__ out)
{
    const int lane = threadIdx.x;
    float contrib = 0.0f;
    if (lane < 32) {
        #pragma unroll
        for (int kk = 0; kk < 10; kk++) {
            float mn = __uint_as_float(~((const unsigned*)red)[kk * 32 + lane]);
            float mx = red[320 + kk * 32 + lane];
            float sm = red[640 + kk * 32 + lane];
            float denom = mx - mn;
            float ss = 1.0f, oo = 0.0f;
            if (denom != 0.0f) { ss = 1.0f / denom; oo = -mn / denom; }
            float w = (float)((kk + 1) * (kk + 1));
            contrib += (ss * sm + oo * 262144.0f) * w;
        }
    }
    for (int off = 16; off > 0; off >>= 1)
        contrib += __shfl_down(contrib, off);
    if (lane == 0) out[0] = contrib / 8388608.0f;
}

extern "C" void kernel_launch(void* const* d_in, const int* in_sizes, int n_in,
                              void* d_out, int out_size, void* d_ws, size_t ws_size,
                              hipStream_t stream)
{
    const float* pred   = (const float*)d_in[0];
    const int*   target = (const int*)d_in[1];
    float* out = (float*)d_out;

    _Float16* h0   = (_Float16*)d_ws;
    _Float16* h1   = h0 + NTOT;
    float*    red  = (float*)(h1 + NTOT);
    unsigned* pcnt = (unsigned*)(red + 960);
    unsigned* done = pcnt + 9 * 32 * 16;

    // zero red + pcnt + done in one shot (min stored as complement -> 0 ok)
    hipMemsetAsync((void*)red, 0, (960 + 9 * 32 * 16 + 16) * 4, stream);

    // persistent path requires all 512 blocks co-resident: occupancy
    // pre-check (host-only, capture-safe), cooperative launch for the
    // residency guarantee (we never call grid.sync).
    static int persist_ok = -1;
    if (persist_ok < 0) {
        int bpc = 0, ncu = 0, dev = 0;
        hipError_t e1 = hipOccupancyMaxActiveBlocksPerMultiprocessor(
            &bpc, (const void*)hausdorff_persist, 512, 0);
        hipGetDevice(&dev);
        hipError_t e2 = hipDeviceGetAttribute(
            &ncu, hipDeviceAttributeMultiprocessorCount, dev);
        persist_ok = (e1 == hipSuccess && e2 == hipSuccess &&
                      bpc * ncu >= 512) ? 1 : 0;
    }

    if (persist_ok) {
        void* args[] = { &pred, &target, &out, &red, &pcnt, &done };
        hipError_t e = hipLaunchCooperativeKernel(
            (void*)hausdorff_persist, dim3(512), dim3(512), args, 0, stream);
        if (e == hipSuccess) return;
    }

    // fallback: round-10-verified multi-launch pipeline (240.8 us)
    dim3 grid(32, 32);
    stencil_first<<<grid, 256, 0, stream>>>(pred, target, h0, red);
    const _Float16* a = h0;
    _Float16*       b = h1;
    for (int k = 1; k < 10; k++) {
        stencil_h<<<grid, 512, 0, stream>>>(a, b, red, k, (k < 9) ? 1 : 0);
        const _Float16* t = a; a = b; b = (_Float16*)t;
    }
    final_out<<<1, 64, 0, stream>>>(red, out);
}

// Round 12
// 242.283 us; speedup vs baseline: 1.0003x; 1.0003x over previous
//
#include <hip/hip_runtime.h>

// Problem constants: B=8, C=4, H=W=512, K_ITERS=10, ALPHA=2
#define Wd   512
#define W4   128
#define W8   64                // half8 granules per row
#define HWp  262144
#define NTOT 8388608

#define NB   16                // blocks per plane (persistent path)
#define OWN  32                // owned rows per block
#define GST  10                // ghost rows per side
#define MAXR 52                // OWN + 2*GST

#define F_INF __int_as_float(0x7F800000)

typedef _Float16 half8 __attribute__((ext_vector_type(8)));
typedef _Float16 half4v __attribute__((ext_vector_type(4)));

// red[]: cmn[k][p]=red[k*32+p] (~bits min); mx=red[320+..]; sm=red[640+..]
// pcnt: 9*32 arrival counters (64B stride); done: final counter

__device__ __forceinline__ float4 bound4(const float* __restrict__ pred,
                                         const int* __restrict__ target,
                                         int plane, int v)
{
    const int b = plane >> 2, c = plane & 3;
    float4 p = ((const float4*)(pred + (size_t)plane * HWp))[v];
    int4   t = ((const int4*)(target + (size_t)b * HWp))[v];
    float dx = p.x - (t.x == c ? 1.0f : 0.0f);
    float dy = p.y - (t.y == c ? 1.0f : 0.0f);
    float dz = p.z - (t.z == c ? 1.0f : 0.0f);
    float dw = p.w - (t.w == c ? 1.0f : 0.0f);
    return make_float4(dx*dx, dy*dy, dz*dz, dw*dw);
}

__device__ __forceinline__ float bound1(const float* __restrict__ pred,
                                        const int* __restrict__ target,
                                        int plane, int i)
{
    const int b = plane >> 2, c = plane & 3;
    float p = pred[(size_t)plane * HWp + i];
    int   t = target[(size_t)b * HWp + i];
    float d = p - (t == c ? 1.0f : 0.0f);
    return d * d;
}

template <int NW>
__device__ __forceinline__ void block_reduce_commit(float lmin, float lmax,
                                                    float lsum,
                                                    float* __restrict__ red,
                                                    int k, int plane)
{
    for (int off = 32; off > 0; off >>= 1) {
        lmin = fminf(lmin, __shfl_down(lmin, off));
        lmax = fmaxf(lmax, __shfl_down(lmax, off));
        lsum += __shfl_down(lsum, off);
    }
    __shared__ float smin[NW], smax[NW], ssum[NW];
    const int wave = threadIdx.x >> 6;
    if ((threadIdx.x & 63) == 0) { smin[wave] = lmin; smax[wave] = lmax; ssum[wave] = lsum; }
    __syncthreads();
    if (threadIdx.x == 0) {
        float bmin = smin[0], bmax = smax[0], bsum = ssum[0];
        #pragma unroll
        for (int i = 1; i < NW; i++) {
            bmin = fminf(bmin, smin[i]);
            bmax = fmaxf(bmax, smax[i]);
            bsum += ssum[i];
        }
        atomicMax((unsigned*)&red[k * 32 + plane], ~__float_as_uint(bmin));
        atomicMax((int*)&red[320 + k * 32 + plane], __float_as_int(bmax));
        atomicAdd(&red[640 + k * 32 + plane], bsum);
    }
}

// ===================== persistent split-phase path =====================
// Per pass: GATHER neighbor-sums (LDS reads only, no sync, independent of
// s,o) -> spin for (s,o) [overlapped with gather skew] -> 1 sync ->
// APPLY fma+relu+write+stats -> commit+arrive -> 1 sync.
// 2 syncthreads/pass vs R11's ~13; barrier wait hidden under gather.
__global__ __launch_bounds__(512) void hausdorff_persist(
    const float* __restrict__ pred, const int* __restrict__ target,
    float* __restrict__ out, float* __restrict__ red,
    unsigned* __restrict__ pcnt, unsigned* __restrict__ done)
{
    const int bid   = blockIdx.x;
    const int plane = bid >> 4;
    const int binp  = bid & 15;
    const int A     = binp * OWN;
    const int rl    = (A - GST < 0) ? 0 : A - GST;
    const int rh    = (A + OWN + GST > Wd) ? Wd : A + OWN + GST;

    const int tid  = threadIdx.x;
    const int lane = tid & 63;
    const int w    = tid >> 6;

    __shared__ _Float16 tile[MAXR][Wd];    // 53 KB
    __shared__ float bc0, bc1;

    const int   b  = plane >> 2, c = plane & 3;
    const float* pp = pred   + (size_t)plane * HWp;
    const int*   tp = target + (size_t)b * HWp;

    // ---- stage bound = (pred-onehot)^2 -> fp16 LDS (inputs read ONCE) ----
    for (int r = rl + w; r < rh; r += 8) {
        const int base = r * Wd + lane * 8;
        float4 p0 = *(const float4*)(pp + base);
        float4 p1 = *(const float4*)(pp + base + 4);
        int4   t0 = *(const int4*)(tp + base);
        int4   t1 = *(const int4*)(tp + base + 4);
        half8 hv;
        float d;
        d = p0.x - (t0.x == c ? 1.0f : 0.0f); hv[0] = (_Float16)(d * d);
        d = p0.y - (t0.y == c ? 1.0f : 0.0f); hv[1] = (_Float16)(d * d);
        d = p0.z - (t0.z == c ? 1.0f : 0.0f); hv[2] = (_Float16)(d * d);
        d = p0.w - (t0.w == c ? 1.0f : 0.0f); hv[3] = (_Float16)(d * d);
        d = p1.x - (t1.x == c ? 1.0f : 0.0f); hv[4] = (_Float16)(d * d);
        d = p1.y - (t1.y == c ? 1.0f : 0.0f); hv[5] = (_Float16)(d * d);
        d = p1.z - (t1.z == c ? 1.0f : 0.0f); hv[6] = (_Float16)(d * d);
        d = p1.w - (t1.w == c ? 1.0f : 0.0f); hv[7] = (_Float16)(d * d);
        ((half8*)&tile[r - rl][0])[lane] = hv;
    }
    __syncthreads();

    const bool hasL = (lane > 0);
    const bool hasR = (lane < W8 - 1);
    const half8 z8 = (half8)(_Float16)0;

// GATHER: neighbor-sums of LDS rows [lo,hi) into G[] (half8 regs).
// Branch on r<hi is wave-uniform (r depends on w,gg only) -> shuffles safe.
#define GATHER(NGMAX, G, lo, hi)                                          \
    _Pragma("unroll")                                                     \
    for (int gg = 0; gg < (NGMAX); gg++) {                                \
        const int r = (lo) + gg * 8 + w;                                  \
        if (r < (hi)) {                                                   \
            const int li = r - rl;                                        \
            half8 c8 = ((const half8*)&tile[li][0])[lane];                \
            half8 u8 = (r > 0)      ? ((const half8*)&tile[li-1][0])[lane] : z8; \
            half8 d8 = (r < Wd - 1) ? ((const half8*)&tile[li+1][0])[lane] : z8; \
            float cf[8], uf[8], df[8];                                    \
            _Pragma("unroll")                                             \
            for (int j = 0; j < 8; j++) {                                 \
                cf[j] = (float)c8[j]; uf[j] = (float)u8[j]; df[j] = (float)d8[j]; \
            }                                                             \
            float lft = __shfl_up(cf[7], 1);                              \
            float rgt = __shfl_down(cf[0], 1);                            \
            if (!hasL) lft = 0.0f;                                        \
            if (!hasR) rgt = 0.0f;                                        \
            half8 g;                                                      \
            _Pragma("unroll")                                             \
            for (int j = 0; j < 8; j++) {                                 \
                const float lnb = (j == 0) ? lft : cf[j - 1];             \
                const float rnb = (j == 7) ? rgt : cf[j + 1];             \
                g[j] = (_Float16)(cf[j] + lnb + rnb + uf[j] + df[j]);     \
            }                                                             \
            (G)[gg] = g;                                                  \
        }                                                                 \
    }

// APPLY: e = relu(0.2*(s*sum + o*cnt) - 0.5); write LDS; stats on owned.
#define APPLY(NGMAX, G, lo, hi, S, O)                                     \
    _Pragma("unroll")                                                     \
    for (int gg = 0; gg < (NGMAX); gg++) {                                \
        const int r = (lo) + gg * 8 + w;                                  \
        if (r < (hi)) {                                                   \
            const int li = r - rl;                                        \
            const float vc = ((r > 0) ? 1.0f : 0.0f) + ((r < Wd-1) ? 1.0f : 0.0f); \
            const bool owned = (r >= A) && (r < A + OWN);                 \
            half8 eh;                                                     \
            _Pragma("unroll")                                             \
            for (int j = 0; j < 8; j++) {                                 \
                const bool hl = (j > 0) || hasL;                          \
                const bool hr = (j < 7) || hasR;                          \
                float cnt = 1.0f + (hl ? 1.0f : 0.0f) + (hr ? 1.0f : 0.0f) + vc; \
                float e = fmaxf(0.2f * ((S) * (float)(G)[gg][j] + (O) * cnt) - 0.5f, 0.0f); \
                _Float16 h = (_Float16)e;                                 \
                eh[j] = h;                                                \
                if (owned) {                                              \
                    float er = (float)h;                                  \
                    lmin = fminf(lmin, er);                               \
                    lmax = fmaxf(lmax, er);                               \
                    lsum += er;                                           \
                }                                                         \
            }                                                             \
            ((half8*)&tile[li][0])[lane] = eh;                            \
        }                                                                 \
    }

    // ---- pass 0: s=1, o=0 known -> gather, sync, apply (margin 9) ----
    {
        const int m  = 9;
        int lo = A - m;        if (lo < 0)  lo = 0;
        int hi = A + OWN + m;  if (hi > Wd) hi = Wd;
        half8 G[7];
        GATHER(7, G, lo, hi)
        __syncthreads();                   // all reads done before writes
        float lmin = F_INF, lmax = 0.0f, lsum = 0.0f;
        APPLY(7, G, lo, hi, 1.0f, 0.0f)
        block_reduce_commit<8>(lmin, lmax, lsum, red, 0, plane);
        if (tid == 0) {
            __threadfence();
            atomicAdd(&pcnt[(0 * 32 + plane) * 16], 1u);
        }
        __syncthreads();                   // writes done before next gather
    }

    // ---- passes 1..9: gather (overlaps barrier skew) -> spin -> apply ----
    for (int k = 1; k < 10; k++) {
        const int m  = 9 - k;
        int lo = A - m;        if (lo < 0)  lo = 0;
        int hi = A + OWN + m;  if (hi > Wd) hi = Wd;

        half8 G[6];
        GATHER(6, G, lo, hi)

        if (tid == 0) {                    // spin for (s_{k-1}, o_{k-1})
            unsigned* ctr = &pcnt[((k - 1) * 32 + plane) * 16];
            unsigned iters = 0;
            while (__hip_atomic_load(ctr, __ATOMIC_RELAXED,
                                     __HIP_MEMORY_SCOPE_AGENT) < (unsigned)NB) {
                __builtin_amdgcn_s_sleep(2);
                if (++iters > (1u << 24)) break;
            }
            __threadfence();               // acquire
            float mn = __uint_as_float(~((volatile unsigned*)red)[(k - 1) * 32 + plane]);
            float mx = ((volatile float*)red)[320 + (k - 1) * 32 + plane];
            float denom = mx - mn;
            float ss = 1.0f, oo = 0.0f;
            if (denom != 0.0f) { ss = 1.0f / denom; oo = -mn / denom; }
            bc0 = ss; bc1 = oo;
        }
        __syncthreads();                   // broadcast + reads-before-writes
        const float s = bc0, o = bc1;

        float lmin = F_INF, lmax = 0.0f, lsum = 0.0f;
        APPLY(6, G, lo, hi, s, o)
        block_reduce_commit<8>(lmin, lmax, lsum, red, k, plane);
        if (tid == 0) {
            __threadfence();
            if (k < 9) atomicAdd(&pcnt[(k * 32 + plane) * 16], 1u);
            else       atomicAdd(done, 1u);
        }
        __syncthreads();                   // writes done before next gather
    }

    // ---- epilogue: block 0 folds red[] into the loss ----
    if (bid != 0) return;
    if (tid == 0) {
        unsigned iters = 0;
        while (__hip_atomic_load(done, __ATOMIC_RELAXED,
                                 __HIP_MEMORY_SCOPE_AGENT) < 512u) {
            __builtin_amdgcn_s_sleep(2);
            if (++iters > (1u << 24)) break;
        }
        __threadfence();
    }
    __syncthreads();
    if (tid < 64) {
        float contrib = 0.0f;
        if (tid < 32) {
            #pragma unroll
            for (int kk = 0; kk < 10; kk++) {
                float mn = __uint_as_float(~((volatile unsigned*)red)[kk * 32 + tid]);
                float mx = ((volatile float*)red)[320 + kk * 32 + tid];
                float sm = ((volatile float*)red)[640 + kk * 32 + tid];
                float denom = mx - mn;
                float ss = 1.0f, oo = 0.0f;
                if (denom != 0.0f) { ss = 1.0f / denom; oo = -mn / denom; }
                float wgt = (float)((kk + 1) * (kk + 1));
                contrib += (ss * sm + oo * 262144.0f) * wgt;
            }
        }
        for (int off = 16; off > 0; off >>= 1)
            contrib += __shfl_down(contrib, off);
        if (tid == 0) out[0] = contrib / 8388608.0f;
    }
}

// ===================== fallback: R10 multi-launch path =====================

__global__ __launch_bounds__(256) void stencil_first(const float* __restrict__ pred,
                                                     const int* __restrict__ target,
                                                     _Float16* __restrict__ out,
                                                     float* __restrict__ red)
{
    const int plane = blockIdx.y;
    const int chunk = blockIdx.x;

    _Float16* op = out + (size_t)plane * HWp;

    const int col4 = threadIdx.x & 127;
    const int rsub = threadIdx.x >> 7;

    float lmin = F_INF, lmax = 0.0f, lsum = 0.0f;
    const bool hasL = (col4 > 0);
    const bool hasR = (col4 < W4 - 1);

    #pragma unroll
    for (int p = 0; p < 8; p++) {
        const int row = chunk * 16 + p * 2 + rsub;
        const int v   = row * W4 + col4;
        const bool hasU = (row > 0);
        const bool hasD = (row < Wd - 1);

        float4 c4 = bound4(pred, target, plane, v);
        float4 u4 = hasU ? bound4(pred, target, plane, v - W4) : make_float4(0,0,0,0);
        float4 d4 = hasD ? bound4(pred, target, plane, v + W4) : make_float4(0,0,0,0);
        float lft = hasL ? bound1(pred, target, plane, 4*v - 1) : 0.0f;
        float rgt = hasR ? bound1(pred, target, plane, 4*v + 4) : 0.0f;

        float4 sum;
        sum.x = c4.x + c4.y + u4.x + d4.x + lft;
        sum.y = c4.x + c4.y + c4.z + u4.y + d4.y;
        sum.z = c4.y + c4.z + c4.w + u4.z + d4.z;
        sum.w = c4.z + c4.w + rgt + u4.w + d4.w;

        float4 e;
        e.x = fmaxf(0.2f * sum.x - 0.5f, 0.0f);
        e.y = fmaxf(0.2f * sum.y - 0.5f, 0.0f);
        e.z = fmaxf(0.2f * sum.z - 0.5f, 0.0f);
        e.w = fmaxf(0.2f * sum.w - 0.5f, 0.0f);

        half4v h;
        h[0] = (_Float16)e.x; h[1] = (_Float16)e.y;
        h[2] = (_Float16)e.z; h[3] = (_Float16)e.w;
        ((half4v*)op)[v] = h;

        float r0 = (float)h[0], r1 = (float)h[1], r2 = (float)h[2], r3 = (float)h[3];
        lmin = fminf(lmin, fminf(fminf(r0, r1), fminf(r2, r3)));
        lmax = fmaxf(lmax, fmaxf(fmaxf(r0, r1), fmaxf(r2, r3)));
        lsum += (r0 + r1) + (r2 + r3);
    }

    block_reduce_commit<4>(lmin, lmax, lsum, red, 0, plane);
}

__global__ __launch_bounds__(512) void stencil_h(const _Float16* __restrict__ in,
                                                 _Float16* __restrict__ out,
                                                 float* __restrict__ red,
                                                 int k, int store)
{
    const int plane = blockIdx.y;
    const int chunk = blockIdx.x;

    float mn = __uint_as_float(~((const unsigned*)red)[(k - 1) * 32 + plane]);
    float mx = red[320 + (k - 1) * 32 + plane];
    float denom = mx - mn;
    float s = 1.0f, o = 0.0f;
    if (denom != 0.0f) { s = 1.0f / denom; o = -mn / denom; }

    const _Float16* ip = in  + (size_t)plane * HWp;
    _Float16*       op = out + (size_t)plane * HWp;

    const int col8 = threadIdx.x & 63;
    const int wv   = threadIdx.x >> 6;
    const int r0   = chunk * 16 + wv * 2;
    const int v0   = r0 * W8 + col8;

    const bool hasL  = (col8 > 0);
    const bool hasR  = (col8 < W8 - 1);
    const bool hasU0 = (r0 > 0);
    const bool hasD1 = (r0 + 2 < Wd);

    half8 u8 = hasU0 ? ((const half8*)ip)[v0 - W8]     : (half8)(_Float16)0;
    half8 c0 = ((const half8*)ip)[v0];
    half8 c1 = ((const half8*)ip)[v0 + W8];
    half8 d8 = hasD1 ? ((const half8*)ip)[v0 + 2 * W8] : (half8)(_Float16)0;

    float uf[8], f0[8], f1[8], df[8];
    #pragma unroll
    for (int j = 0; j < 8; j++) {
        uf[j] = (float)u8[j];
        f0[j] = (float)c0[j]; f1[j] = (float)c1[j];
        df[j] = (float)d8[j];
    }

    float lmin = F_INF, lmax = 0.0f, lsum = 0.0f;

    auto PROC = [&](const float* up, const float* cen, const float* dn, int row) {
        const bool hasU = (row > 0);
        const bool hasD = (row < Wd - 1);
        float lft = __shfl_up(cen[7], 1);
        float rgt = __shfl_down(cen[0], 1);
        if (!hasL) lft = 0.0f;
        if (!hasR) rgt = 0.0f;

        const float vc = (hasU ? 1.0f : 0.0f) + (hasD ? 1.0f : 0.0f);
        half8 eh;
        #pragma unroll
        for (int j = 0; j < 8; j++) {
            const float lnb = (j == 0) ? lft : cen[j - 1];
            const float rnb = (j == 7) ? rgt : cen[j + 1];
            const bool  hl  = (j > 0) || hasL;
            const bool  hr  = (j < 7) || hasR;
            float sum = cen[j] + lnb + rnb + up[j] + dn[j];
            float cnt = 1.0f + (hl ? 1.0f : 0.0f) + (hr ? 1.0f : 0.0f) + vc;
            float e = fmaxf(0.2f * (s * sum + o * cnt) - 0.5f, 0.0f);
            _Float16 h = (_Float16)e;
            eh[j] = h;
            float er = (float)h;
            lmin = fminf(lmin, er);
            lmax = fmaxf(lmax, er);
            lsum += er;
        }
        if (store) ((half8*)op)[row * W8 + col8] = eh;
    };

    PROC(uf, f0, f1, r0);
    PROC(f0, f1, df, r0 + 1);

    block_reduce_commit<8>(lmin, lmax, lsum, red, k, plane);
}

__global__ void final_out(const float* __restrict__ red, float* __restrict__ out)
{
    const int lane = threadIdx.x;
    float contrib = 0.0f;
    if (lane < 32) {
        #pragma unroll
        for (int kk = 0; kk < 10; kk++) {
            float mn = __uint_as_float(~((const unsigned*)red)[kk * 32 + lane]);
            float mx = red[320 + kk * 32 + lane];
            float sm = red[640 + kk * 32 + lane];
            float denom = mx - mn;
            float ss = 1.0f, oo = 0.0f;
            if (denom != 0.0f) { ss = 1.0f / denom; oo = -mn / denom; }
            float w = (float)((kk + 1) * (kk + 1));
            contrib += (ss * sm + oo * 262144.0f) * w;
        }
    }
    for (int off = 16; off > 0; off >>= 1)
        contrib += __shfl_down(contrib, off);
    if (lane == 0) out[0] = contrib / 8388608.0f;
}

extern "C" void kernel_launch(void* const* d_in, const int* in_sizes, int n_in,
                              void* d_out, int out_size, void* d_ws, size_t ws_size,
                              hipStream_t stream)
{
    const float* pred   = (const float*)d_in[0];
    const int*   target = (const int*)d_in[1];
    float* out = (float*)d_out;

    _Float16* h0   = (_Float16*)d_ws;
    _Float16* h1   = h0 + NTOT;
    float*    red  = (float*)(h1 + NTOT);
    unsigned* pcnt = (unsigned*)(red + 960);
    unsigned* done = pcnt + 9 * 32 * 16;

    hipMemsetAsync((void*)red, 0, (960 + 9 * 32 * 16 + 16) * 4, stream);

    static int persist_ok = -1;
    if (persist_ok < 0) {
        int bpc = 0, ncu = 0, dev = 0;
        hipError_t e1 = hipOccupancyMaxActiveBlocksPerMultiprocessor(
            &bpc, (const void*)hausdorff_persist, 512, 0);
        hipGetDevice(&dev);
        hipError_t e2 = hipDeviceGetAttribute(
            &ncu, hipDeviceAttributeMultiprocessorCount, dev);
        persist_ok = (e1 == hipSuccess && e2 == hipSuccess &&
                      bpc * ncu >= 512) ? 1 : 0;
    }

    if (persist_ok) {
        void* args[] = { &pred, &target, &out, &red, &pcnt, &done };
        hipError_t e = hipLaunchCooperativeKernel(
            (void*)hausdorff_persist, dim3(512), dim3(512), args, 0, stream);
        if (e == hipSuccess) return;
    }

    // fallback: round-10-verified multi-launch pipeline (240.8 us)
    dim3 grid(32, 32);
    stencil_first<<<grid, 256, 0, stream>>>(pred, target, h0, red);
    const _Float16* a = h0;
    _Float16*       b = h1;
    for (int k = 1; k < 10; k++) {
        stencil_h<<<grid, 512, 0, stream>>>(a, b, red, k, (k < 9) ? 1 : 0);
        const _Float16* t = a; a = b; b = (_Float16*)t;
    }
    final_out<<<1, 64, 0, stream>>>(red, out);
}